// Round 3
// baseline (262.605 us; speedup 1.0000x reference)
//
#include <hip/hip_runtime.h>
#include <hip/hip_bf16.h>
#include <hip/hip_cooperative_groups.h>
#include <cstdint>
#include <cstddef>

namespace cg = cooperative_groups;

typedef __bf16 bf16_t;
typedef bf16_t bf16x8 __attribute__((ext_vector_type(8)));
typedef float f32x4 __attribute__((ext_vector_type(4)));

#define BN_EPS 1e-5f

// r7: per-lane GLOBAL addresses for global_load_lds must stay lane-order
// contiguous within lines; LDS swizzles only via pre-swizzled SOURCE addrs.
// r8: no __threadfence in epilogues. r10: validate coop launch host-side.
// r11 (REGRESSED): register-direct B doubled B traffic; B must be LDS-staged.
// r12: wave-private gemm1 staging + source-side XOR swizzle: conflicts 7.3M->2.1M
// but dur flat at ~291 — every variant still DRAINED staging before compute
// (vmcnt(0) per step / __syncthreads' implicit vmcnt(0)).
// r13: T4 counted-vmcnt. gemm2: 3-deep rotating buffers, raw s_barrier +
// s_waitcnt vmcnt(12) — 12 loads in flight across barriers, never drained in
// the main loop. gemm1: rotated wave-private stage (issue ks+1 after lgkm(0),
// wait at top of next iter) so the L2 fetch flies under the MFMA block.
__device__ __forceinline__ void async_load16(const bf16_t* g, bf16_t* lds) {
  __builtin_amdgcn_global_load_lds(
      (__attribute__((address_space(1))) uint32_t*)(g),
      (__attribute__((address_space(3))) uint32_t*)(lds),
      16, 0, 0);
}

// ---- Weight prep (transposes + BN folds), tiny ------------------------------
__global__ void prep_weights_kernel(const float* __restrict__ W1, const float* __restrict__ W2,
                                    const float* b1, const float* g1, const float* be1,
                                    const float* m1, const float* v1,
                                    const float* b2, const float* g2, const float* be2,
                                    const float* m2, const float* v2,
                                    bf16_t* __restrict__ W1T, bf16_t* __restrict__ W2T,
                                    float* s1, float* t1, float* s2, float* t2,
                                    float* w1last) {
  const int b = blockIdx.x;
  if (b < 192) {
    const float* src;
    bf16_t* dst;
    int R, C, bx, by;
    if (b < 64) { src = W1; dst = W1T; R = 256; C = 1024; bx = b & 15; by = b >> 4; }
    else        { src = W2; dst = W2T; R = 1024; C = 512; bx = (b - 64) & 7; by = (b - 64) >> 3; }
    __shared__ bf16_t tile[64][66];
    const int r0 = by * 64, c0 = bx * 64;
    const int tc = threadIdx.x & 63;
    const int tr4 = threadIdx.x >> 6;
#pragma unroll
    for (int i = 0; i < 16; ++i) {
      int r = i * 4 + tr4;
      tile[r][tc] = (bf16_t)src[(size_t)(r0 + r) * C + c0 + tc];  // coalesced read
    }
    __syncthreads();
#pragma unroll
    for (int i = 0; i < 16; ++i) {
      int rr = i * 4 + tr4;
      dst[(size_t)(c0 + rr) * R + r0 + tc] = tile[tc][rr];  // coalesced write
    }
  } else {
    for (int i = threadIdx.x; i < 1024; i += 256) {
      float s = g1[i] * rsqrtf(v1[i] + BN_EPS);
      s1[i] = s;
      t1[i] = be1[i] - m1[i] * s + b1[i] * s;  // bn(z+b1) = z*s + t
      w1last[i] = W1[256 * 1024 + i];          // conv-feature row (coalesced)
      if (i < 512) {
        float s2v = g2[i] * rsqrtf(v2[i] + BN_EPS);
        s2[i] = s2v;
        t2[i] = be2[i] - m2[i] * s2v + b2[i] * s2v;
      }
    }
  }
}

// ---- gemm1 body: A-resident in LDS, wave-private rotated B staging ----------
// 128 rows/tile. As = 64 KB (chunk-swizzled). Bs = 4 waves x 4 KB private.
// Per ks: wait vmcnt(0) for the stage issued LAST iteration (in flight during
// last iter's MFMAs), ds_read frags, lgkm(0), issue ks+1's stage, MFMA.
// No barriers in the loop; waves slip freely.
__device__ __forceinline__ void gemm1_body(
    const float* __restrict__ x, const bf16_t* __restrict__ W1T,
    const float* __restrict__ s1, const float* __restrict__ t1,
    const float* __restrict__ w1last, bf16_t* __restrict__ h1,
    unsigned char* smem, int mTile, int lane, int w) {
  bf16_t* As = (bf16_t*)smem;               // [128][256], chunk-swizzled
  bf16_t* Bs = (bf16_t*)(smem + 65536);     // [4 waves][64][32], chunk-swizzled
  float* convs = (float*)(smem + 65536);    // transient overlay (pre-staging)
  const int l15 = lane & 15;
  const int quad = lane >> 4;

  // Prologue: read x fp32, cast->bf16 into As (swizzled), per-row conv.
  {
    const int rsub = lane >> 5;     // 0..1
    const int c = lane & 31;        // 8-elem chunk within row
#pragma unroll
    for (int i = 0; i < 16; ++i) {
      int row = w * 32 + i * 2 + rsub;
      const float* gx = x + (size_t)(mTile + row) * 256 + c * 8;
      const float4 a = *(const float4*)gx;
      const float4 bq = *(const float4*)(gx + 4);
      float s = a.x + a.y + a.z + a.w + bq.x + bq.y + bq.z + bq.w;
      bf16x8 v = {(bf16_t)a.x, (bf16_t)a.y, (bf16_t)a.z, (bf16_t)a.w,
                  (bf16_t)bq.x, (bf16_t)bq.y, (bf16_t)bq.z, (bf16_t)bq.w};
      *(bf16x8*)(As + row * 256 + (c ^ (row & 7)) * 8) = v;
#pragma unroll
      for (int m = 1; m <= 16; m <<= 1) s += __shfl_xor(s, m);  // 32-lane groups
      if (c == 0) convs[row] = (s > 0.0f) ? 1.0f : 0.0f;  // mean>0 <=> sum>0
    }
  }
  __syncthreads();  // As + convs visible

  // Conv feature as a per-lane bitmask over the 32 output rows this lane owns.
  unsigned cmask = 0;
#pragma unroll
  for (int ti = 0; ti < 8; ++ti)
#pragma unroll
    for (int r = 0; r < 4; ++r)
      if (convs[ti * 16 + quad * 4 + r] > 0.5f) cmask |= (1u << (ti * 4 + r));
  __syncthreads();  // all convs readers done before Bs staging overwrites it

  bf16_t* BsW = Bs + w * 2048;          // this wave's private 4 KB region
  const int srow = lane >> 2;           // 0..15 (staging row within 16-group)
  // Pre-swizzled source chunk (within-64B-line permute, r7-safe).
  const int schunk = (lane & 3) ^ ((lane >> 3) & 3);
  const int rchunk = quad ^ ((l15 >> 1) & 3);   // read-side inverse

  for (int j = 0; j < 4; ++j) {
    const int colbase = j * 256 + w * 64;
    f32x4 acc[8][4];
#pragma unroll
    for (int i = 0; i < 8; ++i)
#pragma unroll
      for (int t = 0; t < 4; ++t) {
        f32x4 z = {0.f, 0.f, 0.f, 0.f};
        acc[i][t] = z;
      }

    const bf16_t* gB = W1T + (size_t)(colbase + srow) * 256 + schunk * 8;

    // Prologue stage for ks=0.
#pragma unroll
    for (int i = 0; i < 4; ++i)
      async_load16(gB + (size_t)(i * 16) * 256, BsW + i * 512 + lane * 8);

    for (int ks = 0; ks < 8; ++ks) {
      // Loads for THIS ks were issued last iteration (or just above for ks=0);
      // they've been in flight under the previous MFMA block.
      asm volatile("s_waitcnt vmcnt(0)" ::: "memory");

      bf16x8 af[8], bfr[4];
#pragma unroll
      for (int tj = 0; tj < 4; ++tj)
        bfr[tj] = *(const bf16x8*)(BsW + (tj * 16 + l15) * 32 + rchunk * 8);
#pragma unroll
      for (int ti = 0; ti < 8; ++ti)
        af[ti] = *(const bf16x8*)(As + (ti * 16 + l15) * 256 + ((ks * 4 + quad) ^ (l15 & 7)) * 8);

      // Frags retired -> safe to overwrite the private region with ks+1.
      asm volatile("s_waitcnt lgkmcnt(0)" ::: "memory");
      if (ks < 7) {
#pragma unroll
        for (int i = 0; i < 4; ++i)
          async_load16(gB + (size_t)(i * 16) * 256 + (ks + 1) * 32, BsW + i * 512 + lane * 8);
      }

      __builtin_amdgcn_s_setprio(1);
#pragma unroll
      for (int ti = 0; ti < 8; ++ti)
#pragma unroll
        for (int tj = 0; tj < 4; ++tj)
          acc[ti][tj] = __builtin_amdgcn_mfma_f32_16x16x32_bf16(af[ti], bfr[tj], acc[ti][tj], 0, 0, 0);
      __builtin_amdgcn_s_setprio(0);
    }

    // Per-chunk epilogue: conv rank-1 + BN1 + ReLU -> h1 (bf16)
    float sc[4], tcv[4], wl[4];
#pragma unroll
    for (int tj = 0; tj < 4; ++tj) {
      int c = colbase + tj * 16 + l15;
      sc[tj] = s1[c];
      tcv[tj] = t1[c];
      wl[tj] = w1last[c];
    }
#pragma unroll
    for (int ti = 0; ti < 8; ++ti)
#pragma unroll
      for (int r = 0; r < 4; ++r) {
        int row = mTile + ti * 16 + quad * 4 + r;
        size_t base = (size_t)row * 1024 + colbase;
        const float cfv = ((cmask >> (ti * 4 + r)) & 1u) ? 1.0f : 0.0f;
#pragma unroll
        for (int tj = 0; tj < 4; ++tj) {
          float z = acc[ti][tj][r] + cfv * wl[tj];
          z = fmaxf(z * sc[tj] + tcv[tj], 0.f);
          h1[base + tj * 16 + l15] = (bf16_t)z;
        }
      }
  }
}

// ---- gemm2 task body: one 256x128 tile -> per-N partials --------------------
// 3-deep rotating LDS buffers (3 x (As 16K + Bs 8K) = 72 KB). Counted-vmcnt
// pipeline: stage k+2 each step, wait vmcnt(12) (stages k+1,k+2 stay in
// flight), raw s_barrier. vmcnt never drains to 0 until the 2-step tail.
// WAR on recycled buffer: end-of-iter barrier + MFMA-consumption dataflow
// guarantee all waves' ds_reads of that buffer retired before restage.
__device__ __forceinline__ void gemm2_task_body(
    const bf16_t* __restrict__ h1, const bf16_t* __restrict__ W2T,
    const float* __restrict__ s2, const float* __restrict__ t2,
    const float* __restrict__ W3, float* __restrict__ partials,
    unsigned char* smem, int task, int lane, int w) {
  bf16_t* As2 = (bf16_t*)smem;             // [3][256][32] swizzled
  bf16_t* Bs2 = (bf16_t*)(smem + 49152);   // [3][128][32] swizzled
  const int l15 = lane & 15;
  const int quad = lane >> 4;
  const int sRow = lane >> 2;
  const int sColSwz = ((lane & 3) ^ ((lane >> 3) & 3)) * 8;  // pre-swizzled src
  const int rchunk8 = (quad ^ ((l15 >> 1) & 3)) * 8;         // read-side inverse

  const int mt = (task >> 5) * 8 + (task & 7);   // XCD-grouped M-tile
  const int mTile2 = mt * 256;
  const int nt = (task >> 3) & 3;
  const int nTile = nt * 128;

  const bf16_t* gA = h1 + (size_t)(mTile2 + w * 64 + sRow) * 1024 + sColSwz;
  const bf16_t* gB = W2T + (size_t)(nTile + w * 32 + sRow) * 1024 + sColSwz;
  bf16_t* lA0 = As2 + (w * 64) * 32;
  bf16_t* lB0 = Bs2 + (w * 32) * 32;

  f32x4 acc[4][8];
#pragma unroll
  for (int i = 0; i < 4; ++i)
#pragma unroll
    for (int j = 0; j < 8; ++j) {
      f32x4 z = {0.f, 0.f, 0.f, 0.f};
      acc[i][j] = z;
    }

  // Protect LDS against the previous phase's in-flight readers; also ensures
  // vmcnt==0 at pipeline start so the counted waits below are exact.
  __syncthreads();

#define STAGE2(aoff, boff, k0)                                              \
  do {                                                                      \
    bf16_t* lA = lA0 + (aoff);                                              \
    bf16_t* lB = lB0 + (boff);                                              \
    async_load16(gA + (k0), lA);                                            \
    async_load16(gA + (size_t)16 * 1024 + (k0), lA + 16 * 32);              \
    async_load16(gA + (size_t)32 * 1024 + (k0), lA + 32 * 32);              \
    async_load16(gA + (size_t)48 * 1024 + (k0), lA + 48 * 32);              \
    async_load16(gB + (k0), lB);                                            \
    async_load16(gB + (size_t)16 * 1024 + (k0), lB + 16 * 32);              \
  } while (0)

  STAGE2(0, 0, 0);          // k=0 -> buffer 0   (6 in flight)
  STAGE2(8192, 4096, 32);   // k=1 -> buffer 1   (12 in flight)

  int aCur = 0, aN1 = 8192, aN2 = 16384;
  int bCur = 0, bN1 = 4096, bN2 = 8192;

  for (int t = 0; t < 32; ++t) {
    if (t < 30) {
      STAGE2(aN2, bN2, (t + 2) * 32);  // stage k=t+2 into recycled buffer
      asm volatile("s_waitcnt vmcnt(12)" ::: "memory");  // k=t landed; k+1,k+2 fly
    } else if (t == 30) {
      asm volatile("s_waitcnt vmcnt(6)" ::: "memory");
    } else {
      asm volatile("s_waitcnt vmcnt(0)" ::: "memory");
    }
    asm volatile("s_barrier" ::: "memory");  // all waves' stage-t visible

    bf16x8 af[4], bfr[8];
#pragma unroll
    for (int ti = 0; ti < 4; ++ti)
      af[ti] = *(const bf16x8*)(As2 + aCur + (w * 64 + ti * 16 + l15) * 32 + rchunk8);
#pragma unroll
    for (int tj = 0; tj < 8; ++tj)
      bfr[tj] = *(const bf16x8*)(Bs2 + bCur + (tj * 16 + l15) * 32 + rchunk8);

    __builtin_amdgcn_s_setprio(1);
#pragma unroll
    for (int ti = 0; ti < 4; ++ti)
#pragma unroll
      for (int tj = 0; tj < 8; ++tj)
        acc[ti][tj] = __builtin_amdgcn_mfma_f32_16x16x32_bf16(af[ti], bfr[tj], acc[ti][tj], 0, 0, 0);
    __builtin_amdgcn_s_setprio(0);

    asm volatile("s_barrier" ::: "memory");  // reads of buf t retired everywhere

    int tmp = aCur; aCur = aN1; aN1 = aN2; aN2 = tmp;
    tmp = bCur; bCur = bN1; bN1 = bN2; bN2 = tmp;
  }
#undef STAGE2

  float sc[8], tcs[8], w3c[8];
#pragma unroll
  for (int tj = 0; tj < 8; ++tj) {
    int c = nTile + tj * 16 + l15;
    sc[tj] = s2[c];
    tcs[tj] = t2[c];
    w3c[tj] = W3[c];
  }
#pragma unroll
  for (int ti = 0; ti < 4; ++ti)
#pragma unroll
    for (int r = 0; r < 4; ++r) {
      float pv = 0.f;
#pragma unroll
      for (int tj = 0; tj < 8; ++tj) {
        float z = fmaxf(acc[ti][tj][r] * sc[tj] + tcs[tj], 0.f);
        pv += z * w3c[tj];
      }
#pragma unroll
      for (int m = 1; m <= 8; m <<= 1) pv += __shfl_xor(pv, m);
      if (l15 == 0)
        partials[(size_t)nt * 65536 + mTile2 + w * 64 + ti * 16 + quad * 4 + r] = pv;
    }
}

// ---- Standalone wrappers (fallback path) ------------------------------------
__global__ __launch_bounds__(256, 2) void gemm1_kernel(
    const float* __restrict__ x, const bf16_t* __restrict__ W1T,
    const float* __restrict__ s1, const float* __restrict__ t1,
    const float* __restrict__ w1last, bf16_t* __restrict__ h1) {
  __shared__ __align__(16) unsigned char smem[81920];
  gemm1_body(x, W1T, s1, t1, w1last, h1, smem, blockIdx.x * 128,
             threadIdx.x & 63, threadIdx.x >> 6);
}

__global__ __launch_bounds__(256, 2) void gemm2_kernel(
    const bf16_t* __restrict__ h1, const bf16_t* __restrict__ W2T,
    const float* __restrict__ s2, const float* __restrict__ t2,
    const float* __restrict__ W3, float* __restrict__ partials) {
  __shared__ __align__(16) unsigned char smem[73728];
  gemm2_task_body(h1, W2T, s2, t2, W3, partials, smem, blockIdx.x,
                  threadIdx.x & 63, threadIdx.x >> 6);
}

__global__ void sigmoid_partials_kernel(const float* __restrict__ partials,
                                        const float* __restrict__ b3,
                                        float* __restrict__ out) {
  int i = blockIdx.x * 256 + threadIdx.x;
  float z = partials[i] + partials[65536 + i] + partials[2 * 65536 + i] +
            partials[3 * 65536 + i] + b3[0];
  out[i] = 1.0f / (1.0f + expf(-z));
}

// ---- Cooperative fused path -------------------------------------------------
__global__ __launch_bounds__(256, 2) void fused_mlp_coop(
    const float* __restrict__ x,
    const bf16_t* __restrict__ W1T, const bf16_t* __restrict__ W2T,
    const float* __restrict__ s1, const float* __restrict__ t1,
    const float* __restrict__ w1last,
    const float* __restrict__ s2, const float* __restrict__ t2,
    const float* __restrict__ W3, const float* __restrict__ b3,
    bf16_t* __restrict__ h1, float* __restrict__ partials,
    float* __restrict__ out) {
  __shared__ __align__(16) unsigned char smem[81920];
  cg::grid_group grid = cg::this_grid();
  const int tid = threadIdx.x;
  const int lane = tid & 63;
  const int w = tid >> 6;

  gemm1_body(x, W1T, s1, t1, w1last, h1, smem, blockIdx.x * 128, lane, w);

  grid.sync();  // h1 visible grid-wide (also block-syncs LDS handoff)

  gemm2_task_body(h1, W2T, s2, t2, W3, partials, smem, blockIdx.x, lane, w);
  gemm2_task_body(h1, W2T, s2, t2, W3, partials, smem, blockIdx.x + 512, lane, w);

  grid.sync();  // partials visible

  if (tid < 128) {
    int r = blockIdx.x * 128 + tid;
    float z = partials[r] + partials[65536 + r] + partials[2 * 65536 + r] +
              partials[3 * 65536 + r] + b3[0];
    out[r] = 1.0f / (1.0f + expf(-z));
  }
}

extern "C" void kernel_launch(void* const* d_in, const int* in_sizes, int n_in,
                              void* d_out, int out_size, void* d_ws, size_t ws_size,
                              hipStream_t stream) {
  const float* x = (const float*)d_in[0];
  const float* W1 = (const float*)d_in[1];
  const float* b1 = (const float*)d_in[2];
  const float* g1 = (const float*)d_in[3];
  const float* be1 = (const float*)d_in[4];
  const float* m1 = (const float*)d_in[5];
  const float* v1 = (const float*)d_in[6];
  const float* W2 = (const float*)d_in[7];
  const float* b2 = (const float*)d_in[8];
  const float* g2 = (const float*)d_in[9];
  const float* be2 = (const float*)d_in[10];
  const float* m2 = (const float*)d_in[11];
  const float* v2 = (const float*)d_in[12];
  const float* W3 = (const float*)d_in[13];
  const float* b3 = (const float*)d_in[14];
  float* out = (float*)d_out;

  char* p = (char*)d_ws;
  bf16_t* h1 = (bf16_t*)p;       p += (size_t)65536 * 1024 * 2;  // 128 MB
  float* partials = (float*)p;   p += (size_t)4 * 65536 * 4;     // 1 MB
  bf16_t* W1T = (bf16_t*)p;      p += (size_t)1024 * 256 * 2;
  bf16_t* W2T = (bf16_t*)p;      p += (size_t)512 * 1024 * 2;
  float* w1last = (float*)p;     p += 1024 * 4;
  float* s1 = (float*)p;         p += 1024 * 4;
  float* t1 = (float*)p;         p += 1024 * 4;
  float* s2 = (float*)p;         p += 512 * 4;
  float* t2 = (float*)p;         p += 512 * 4;

  prep_weights_kernel<<<193, 256, 0, stream>>>(W1, W2, b1, g1, be1, m1, v1,
                                               b2, g2, be2, m2, v2,
                                               W1T, W2T, s1, t1, s2, t2, w1last);

  // Host-side (capture-safe) validation of the cooperative path.
  int dev = 0;
  (void)hipGetDevice(&dev);
  int coopOk = 0;
  (void)hipDeviceGetAttribute(&coopOk, hipDeviceAttributeCooperativeLaunch, dev);
  int numCU = 0;
  (void)hipDeviceGetAttribute(&numCU, hipDeviceAttributeMultiprocessorCount, dev);
  int maxBlk = 0;
  (void)hipOccupancyMaxActiveBlocksPerMultiprocessor(&maxBlk, fused_mlp_coop, 256, 0);

  bool useCoop = (coopOk != 0) && ((long)maxBlk * (long)numCU >= 512L);
  if (useCoop) {
    void* args[] = {(void*)&x, (void*)&W1T, (void*)&W2T, (void*)&s1, (void*)&t1,
                    (void*)&w1last, (void*)&s2, (void*)&t2, (void*)&W3, (void*)&b3,
                    (void*)&h1, (void*)&partials, (void*)&out};
    hipError_t e = hipLaunchCooperativeKernel((const void*)fused_mlp_coop,
                                              dim3(512), dim3(256), args, 0, stream);
    if (e != hipSuccess) useCoop = false;
  }
  if (!useCoop) {
    gemm1_kernel<<<512, 256, 0, stream>>>(x, W1T, s1, t1, w1last, h1);
    gemm2_kernel<<<1024, 256, 0, stream>>>(h1, W2T, s2, t2, W3, partials);
    sigmoid_partials_kernel<<<256, 256, 0, stream>>>(partials, b3, out);
  }
}

// Round 4
// 261.518 us; speedup vs baseline: 1.0042x; 1.0042x over previous
//
#include <hip/hip_runtime.h>
#include <hip/hip_bf16.h>
#include <cstdint>
#include <cstddef>

typedef __bf16 bf16_t;
typedef bf16_t bf16x8 __attribute__((ext_vector_type(8)));
typedef float f32x4 __attribute__((ext_vector_type(4)));

#define BN_EPS 1e-5f

// r7: per-lane GLOBAL addresses for global_load_lds must stay lane-order
// contiguous within lines; LDS swizzles only via pre-swizzled SOURCE addrs.
// r8: no __threadfence in epilogues. r10: coop launches need host validation.
// r11 (REGRESSED): register-direct B doubled B traffic; B must be LDS-staged.
// r12/r13: swizzle killed bank conflicts (7.3M->2.1M) but ALL inner-loop
// schedule variants (drain / wave-private / counted-vmcnt 3-deep) land at
// 290-302 us. Inner K-loop scheduling is not the bottleneck.
// r14: structural — (1) full per-block fusion (64 rows end-to-end), no coop,
// no grid.sync, no partials: block writes its h1 tile, reads it back (L2-warm)
// for gemm2 over its own rows, reduces with W3 in-block, writes out directly.
// (2) occupancy 2->3 blocks/CU: 48KB LDS + 64-AGPR accumulators +
// __launch_bounds__(256,3) -> 12 waves/CU of TLP to hide latency.
__device__ __forceinline__ void async_load16(const bf16_t* g, bf16_t* lds) {
  __builtin_amdgcn_global_load_lds(
      (__attribute__((address_space(1))) uint32_t*)(g),
      (__attribute__((address_space(3))) uint32_t*)(lds),
      16, 0, 0);
}

// ---- Weight prep (transposes + BN folds), tiny ------------------------------
__global__ void prep_weights_kernel(const float* __restrict__ W1, const float* __restrict__ W2,
                                    const float* b1, const float* g1, const float* be1,
                                    const float* m1, const float* v1,
                                    const float* b2, const float* g2, const float* be2,
                                    const float* m2, const float* v2,
                                    bf16_t* __restrict__ W1T, bf16_t* __restrict__ W2T,
                                    float* s1, float* t1, float* s2, float* t2,
                                    float* w1last) {
  const int b = blockIdx.x;
  if (b < 192) {
    const float* src;
    bf16_t* dst;
    int R, C, bx, by;
    if (b < 64) { src = W1; dst = W1T; R = 256; C = 1024; bx = b & 15; by = b >> 4; }
    else        { src = W2; dst = W2T; R = 1024; C = 512; bx = (b - 64) & 7; by = (b - 64) >> 3; }
    __shared__ bf16_t tile[64][66];
    const int r0 = by * 64, c0 = bx * 64;
    const int tc = threadIdx.x & 63;
    const int tr4 = threadIdx.x >> 6;
#pragma unroll
    for (int i = 0; i < 16; ++i) {
      int r = i * 4 + tr4;
      tile[r][tc] = (bf16_t)src[(size_t)(r0 + r) * C + c0 + tc];  // coalesced read
    }
    __syncthreads();
#pragma unroll
    for (int i = 0; i < 16; ++i) {
      int rr = i * 4 + tr4;
      dst[(size_t)(c0 + rr) * R + r0 + tc] = tile[tc][rr];  // coalesced write
    }
  } else {
    for (int i = threadIdx.x; i < 1024; i += 256) {
      float s = g1[i] * rsqrtf(v1[i] + BN_EPS);
      s1[i] = s;
      t1[i] = be1[i] - m1[i] * s + b1[i] * s;  // bn(z+b1) = z*s + t
      w1last[i] = W1[256 * 1024 + i];          // conv-feature row (coalesced)
      if (i < 512) {
        float s2v = g2[i] * rsqrtf(v2[i] + BN_EPS);
        s2[i] = s2v;
        t2[i] = be2[i] - m2[i] * s2v + b2[i] * s2v;
      }
    }
  }
}

// ---- Fused per-block MLP: 64 rows end-to-end --------------------------------
// LDS (48 KB): gemm1 phase: As[64][256] (32 KB) + Bs[4 waves][64][32] (16 KB,
// convs[64] overlays Bs pre-staging). gemm2 phase: A2[2][64][32] (8 KB) +
// B2[2][256][32] (32 KB) + outW[4][64] (1 KB) — reuses the same arena.
__global__ __launch_bounds__(256, 3) void fused_mlp(
    const float* __restrict__ x,
    const bf16_t* __restrict__ W1T, const bf16_t* __restrict__ W2T,
    const float* __restrict__ s1, const float* __restrict__ t1,
    const float* __restrict__ w1last,
    const float* __restrict__ s2, const float* __restrict__ t2,
    const float* __restrict__ W3, const float* __restrict__ b3,
    bf16_t* __restrict__ h1, float* __restrict__ out) {
  __shared__ __align__(16) unsigned char smem[49152];
  const int tid = threadIdx.x;
  const int lane = tid & 63;
  const int w = tid >> 6;
  const int l15 = lane & 15;
  const int quad = lane >> 4;
  const int mTile = blockIdx.x * 64;

  bf16_t* As = (bf16_t*)smem;               // [64][256], chunk-swizzled (32 KB)
  bf16_t* Bs = (bf16_t*)(smem + 32768);     // [4 waves][64][32] (16 KB)
  float* convs = (float*)(smem + 32768);    // transient overlay (pre-staging)

  // ---- gemm1 prologue: x fp32 -> bf16 into As (swizzled), per-row conv ----
  {
    const int rsub = lane >> 5;     // 0..1
    const int c = lane & 31;        // 8-elem chunk within row
#pragma unroll
    for (int i = 0; i < 8; ++i) {
      int row = w * 16 + i * 2 + rsub;
      const float* gx = x + (size_t)(mTile + row) * 256 + c * 8;
      const float4 a = *(const float4*)gx;
      const float4 bq = *(const float4*)(gx + 4);
      float s = a.x + a.y + a.z + a.w + bq.x + bq.y + bq.z + bq.w;
      bf16x8 v = {(bf16_t)a.x, (bf16_t)a.y, (bf16_t)a.z, (bf16_t)a.w,
                  (bf16_t)bq.x, (bf16_t)bq.y, (bf16_t)bq.z, (bf16_t)bq.w};
      *(bf16x8*)(As + row * 256 + (c ^ (row & 7)) * 8) = v;
#pragma unroll
      for (int m = 1; m <= 16; m <<= 1) s += __shfl_xor(s, m);  // 32-lane groups
      if (c == 0) convs[row] = (s > 0.0f) ? 1.0f : 0.0f;  // mean>0 <=> sum>0
    }
  }
  __syncthreads();  // As + convs visible

  // Conv feature as a per-lane bitmask over the 16 output rows this lane owns.
  unsigned cmask = 0;
#pragma unroll
  for (int ti = 0; ti < 4; ++ti)
#pragma unroll
    for (int r = 0; r < 4; ++r)
      if (convs[ti * 16 + quad * 4 + r] > 0.5f) cmask |= (1u << (ti * 4 + r));
  __syncthreads();  // convs readers done before Bs staging overwrites it

  bf16_t* BsW = Bs + w * 2048;          // this wave's private 4 KB region
  const int srow = lane >> 2;           // 0..15
  const int schunk = (lane & 3) ^ ((lane >> 3) & 3);   // pre-swizzled src chunk
  const int rchunk = quad ^ ((l15 >> 1) & 3);          // read-side inverse

  // ---- gemm1: wave w owns cols j*256 + w*64 .. +63, rotated private stage ---
  for (int j = 0; j < 4; ++j) {
    const int colbase = j * 256 + w * 64;
    f32x4 acc[4][4];
#pragma unroll
    for (int i = 0; i < 4; ++i)
#pragma unroll
      for (int t = 0; t < 4; ++t) {
        f32x4 z = {0.f, 0.f, 0.f, 0.f};
        acc[i][t] = z;
      }

    const bf16_t* gB = W1T + (size_t)(colbase + srow) * 256 + schunk * 8;

#pragma unroll
    for (int i = 0; i < 4; ++i)
      async_load16(gB + (size_t)(i * 16) * 256, BsW + i * 512 + lane * 8);

    for (int ks = 0; ks < 8; ++ks) {
      asm volatile("s_waitcnt vmcnt(0)" ::: "memory");  // per-wave, no barrier

      bf16x8 af[4], bfr[4];
#pragma unroll
      for (int tj = 0; tj < 4; ++tj)
        bfr[tj] = *(const bf16x8*)(BsW + (tj * 16 + l15) * 32 + rchunk * 8);
#pragma unroll
      for (int ti = 0; ti < 4; ++ti)
        af[ti] = *(const bf16x8*)(As + (ti * 16 + l15) * 256 + ((ks * 4 + quad) ^ (l15 & 7)) * 8);

      asm volatile("s_waitcnt lgkmcnt(0)" ::: "memory");  // frags in regs
      if (ks < 7) {
#pragma unroll
        for (int i = 0; i < 4; ++i)
          async_load16(gB + (size_t)(i * 16) * 256 + (ks + 1) * 32, BsW + i * 512 + lane * 8);
      }

      __builtin_amdgcn_s_setprio(1);
#pragma unroll
      for (int ti = 0; ti < 4; ++ti)
#pragma unroll
        for (int tj = 0; tj < 4; ++tj)
          acc[ti][tj] = __builtin_amdgcn_mfma_f32_16x16x32_bf16(af[ti], bfr[tj], acc[ti][tj], 0, 0, 0);
      __builtin_amdgcn_s_setprio(0);
    }

    // Epilogue: conv rank-1 + BN1 + ReLU -> h1 tile (bf16)
    float sc[4], tcv[4], wl[4];
#pragma unroll
    for (int tj = 0; tj < 4; ++tj) {
      int c = colbase + tj * 16 + l15;
      sc[tj] = s1[c];
      tcv[tj] = t1[c];
      wl[tj] = w1last[c];
    }
#pragma unroll
    for (int ti = 0; ti < 4; ++ti)
#pragma unroll
      for (int r = 0; r < 4; ++r) {
        int row = mTile + ti * 16 + quad * 4 + r;
        size_t base = (size_t)row * 1024 + colbase;
        const float cfv = ((cmask >> (ti * 4 + r)) & 1u) ? 1.0f : 0.0f;
#pragma unroll
        for (int tj = 0; tj < 4; ++tj) {
          float z = acc[ti][tj][r] + cfv * wl[tj];
          z = fmaxf(z * sc[tj] + tcv[tj], 0.f);
          h1[base + tj * 16 + l15] = (bf16_t)z;
        }
      }
  }

  // Drain h1 stores before gemm2 stages them back (plus barrier below).
  asm volatile("s_waitcnt vmcnt(0)" ::: "memory");

  // ---- gemm2 fused: block's own 64 rows x 512 cols, K=1024 ----------------
  bf16_t* A2 = (bf16_t*)smem;               // [2][64][32]  (2 x 4 KB)
  bf16_t* B2 = (bf16_t*)(smem + 8192);      // [2][256][32] (2 x 16 KB)
  float* outW = (float*)(smem + 40960);     // [4][64]
  const int rchunk8 = rchunk * 8;
  const int sColSwz = schunk * 8;

  float rowpv[4][4];
#pragma unroll
  for (int ti = 0; ti < 4; ++ti)
#pragma unroll
    for (int r = 0; r < 4; ++r) rowpv[ti][r] = 0.f;

  for (int nt = 0; nt < 2; ++nt) {
    __syncthreads();  // LDS WAR protect + full drain (counted waits exact)

    const bf16_t* gA = h1 + (size_t)(mTile + w * 16 + srow) * 1024 + sColSwz;
    const bf16_t* gB2 = W2T + (size_t)(nt * 256 + w * 64 + srow) * 1024 + sColSwz;

    f32x4 acc2[4][4];
#pragma unroll
    for (int i = 0; i < 4; ++i)
#pragma unroll
      for (int t = 0; t < 4; ++t) {
        f32x4 z = {0.f, 0.f, 0.f, 0.f};
        acc2[i][t] = z;
      }

#define STAGE2(buf, k0)                                                       \
  do {                                                                        \
    async_load16(gA + (k0), A2 + (buf)*2048 + w * 512 + lane * 8);            \
    async_load16(gB2 + (k0), B2 + (buf)*8192 + w * 2048 + lane * 8);          \
    async_load16(gB2 + (size_t)16 * 1024 + (k0),                              \
                 B2 + (buf)*8192 + w * 2048 + 512 + lane * 8);                \
    async_load16(gB2 + (size_t)32 * 1024 + (k0),                              \
                 B2 + (buf)*8192 + w * 2048 + 1024 + lane * 8);               \
    async_load16(gB2 + (size_t)48 * 1024 + (k0),                              \
                 B2 + (buf)*8192 + w * 2048 + 1536 + lane * 8);               \
  } while (0)

    STAGE2(0, 0);  // 5 loads in flight
    int buf = 0;
    for (int t = 0; t < 32; ++t) {
      if (t < 31) {
        STAGE2(buf ^ 1, (t + 1) * 32);                    // 10 in flight
        asm volatile("s_waitcnt vmcnt(5)" ::: "memory");  // stage t landed
      } else {
        asm volatile("s_waitcnt vmcnt(0)" ::: "memory");
      }
      asm volatile("s_barrier" ::: "memory");  // all waves' stage-t visible

      bf16x8 af[4], bfr[4];
#pragma unroll
      for (int ti = 0; ti < 4; ++ti)
        af[ti] = *(const bf16x8*)(A2 + buf * 2048 + (ti * 16 + l15) * 32 + rchunk8);
#pragma unroll
      for (int tj = 0; tj < 4; ++tj)
        bfr[tj] = *(const bf16x8*)(B2 + buf * 8192 + (w * 64 + tj * 16 + l15) * 32 + rchunk8);

      __builtin_amdgcn_s_setprio(1);
#pragma unroll
      for (int ti = 0; ti < 4; ++ti)
#pragma unroll
        for (int tj = 0; tj < 4; ++tj)
          acc2[ti][tj] = __builtin_amdgcn_mfma_f32_16x16x32_bf16(af[ti], bfr[tj], acc2[ti][tj], 0, 0, 0);
      __builtin_amdgcn_s_setprio(0);

      asm volatile("s_barrier" ::: "memory");  // reads of buf retired everywhere
      buf ^= 1;
    }
#undef STAGE2

    // Per-pass epilogue: BN2 + ReLU + dot with W3 over this wave's 64 cols.
    float sc[4], tcs[4], w3c[4];
#pragma unroll
    for (int tj = 0; tj < 4; ++tj) {
      int c = nt * 256 + w * 64 + tj * 16 + l15;
      sc[tj] = s2[c];
      tcs[tj] = t2[c];
      w3c[tj] = W3[c];
    }
#pragma unroll
    for (int ti = 0; ti < 4; ++ti)
#pragma unroll
      for (int r = 0; r < 4; ++r) {
        float pv = 0.f;
#pragma unroll
        for (int tj = 0; tj < 4; ++tj) {
          float z = fmaxf(acc2[ti][tj][r] * sc[tj] + tcs[tj], 0.f);
          pv += z * w3c[tj];
        }
#pragma unroll
        for (int m = 1; m <= 8; m <<= 1) pv += __shfl_xor(pv, m);
        rowpv[ti][r] += pv;
      }
  }

  // Cross-wave reduce (each wave covered a disjoint 64-col group of N=512).
  if (l15 == 0) {
#pragma unroll
    for (int ti = 0; ti < 4; ++ti)
#pragma unroll
      for (int r = 0; r < 4; ++r)
        outW[w * 64 + ti * 16 + quad * 4 + r] = rowpv[ti][r];
  }
  __syncthreads();
  if (tid < 64) {
    float z = outW[tid] + outW[64 + tid] + outW[128 + tid] + outW[192 + tid] + b3[0];
    out[mTile + tid] = 1.0f / (1.0f + expf(-z));
  }
}

extern "C" void kernel_launch(void* const* d_in, const int* in_sizes, int n_in,
                              void* d_out, int out_size, void* d_ws, size_t ws_size,
                              hipStream_t stream) {
  const float* x = (const float*)d_in[0];
  const float* W1 = (const float*)d_in[1];
  const float* b1 = (const float*)d_in[2];
  const float* g1 = (const float*)d_in[3];
  const float* be1 = (const float*)d_in[4];
  const float* m1 = (const float*)d_in[5];
  const float* v1 = (const float*)d_in[6];
  const float* W2 = (const float*)d_in[7];
  const float* b2 = (const float*)d_in[8];
  const float* g2 = (const float*)d_in[9];
  const float* be2 = (const float*)d_in[10];
  const float* m2 = (const float*)d_in[11];
  const float* v2 = (const float*)d_in[12];
  const float* W3 = (const float*)d_in[13];
  const float* b3 = (const float*)d_in[14];
  float* out = (float*)d_out;

  char* p = (char*)d_ws;
  bf16_t* h1 = (bf16_t*)p;       p += (size_t)65536 * 1024 * 2;  // 128 MB
  float* partials = (float*)p;   p += (size_t)4 * 65536 * 4;     // 1 MB (unused, layout kept)
  bf16_t* W1T = (bf16_t*)p;      p += (size_t)1024 * 256 * 2;
  bf16_t* W2T = (bf16_t*)p;      p += (size_t)512 * 1024 * 2;
  float* w1last = (float*)p;     p += 1024 * 4;
  float* s1 = (float*)p;         p += 1024 * 4;
  float* t1 = (float*)p;         p += 1024 * 4;
  float* s2 = (float*)p;         p += 512 * 4;
  float* t2 = (float*)p;         p += 512 * 4;
  (void)partials;

  prep_weights_kernel<<<193, 256, 0, stream>>>(W1, W2, b1, g1, be1, m1, v1,
                                               b2, g2, be2, m2, v2,
                                               W1T, W2T, s1, t1, s2, t2, w1last);

  fused_mlp<<<1024, 256, 0, stream>>>(x, W1T, W2T, s1, t1, w1last,
                                      s2, t2, W3, b3, h1, out);
}